// Round 1
// 1531.576 us; speedup vs baseline: 1.8163x; 1.8163x over previous
//
#include <hip/hip_runtime.h>
#include <hip/hip_bf16.h>
#include <stdint.h>

typedef __bf16 bf16x8  __attribute__((ext_vector_type(8)));
typedef float  floatx4 __attribute__((ext_vector_type(4)));
typedef int    intx4   __attribute__((ext_vector_type(4)));
typedef unsigned int uintx4 __attribute__((ext_vector_type(4)));

constexpr int BM = 128;
constexpr int BN = 128;
constexpr int BK = 32;   // one 16x16x32 MFMA K-step per LDS buffer

// ---------------------------------------------------------------------------
// Stage 1a: A fp32 -> bf16 (same rounding as the fused kernel did per-tile).
// ---------------------------------------------------------------------------
__global__ __launch_bounds__(256)
void conv_a(const float* __restrict__ A, __bf16* __restrict__ Ab, long n8)
{
    long id = (long)blockIdx.x * 256 + threadIdx.x;
    if (id >= n8) return;
    const float* p = A + id * 8;
    floatx4 f0 = *(const floatx4*)p;
    floatx4 f1 = *(const floatx4*)(p + 4);
    bf16x8 o;
#pragma unroll
    for (int e = 0; e < 4; e++) o[e]     = (__bf16)f0[e];
#pragma unroll
    for (int e = 0; e < 4; e++) o[4 + e] = (__bf16)f1[e];
    *(bf16x8*)(Ab + id * 8) = o;
}

// ---------------------------------------------------------------------------
// Stage 1b: W int32 * scale -> bf16 (identical arithmetic to the fused path:
// (float)int8 * sc rounded to bf16). Halves W's HBM footprint (180->90 MB).
// ---------------------------------------------------------------------------
__global__ __launch_bounds__(256)
void conv_w(const int* __restrict__ Wq, const float* __restrict__ scales,
            __bf16* __restrict__ Wb, int K, int numGroups, long n8)
{
    long id = (long)blockIdx.x * 256 + threadIdx.x;
    if (id >= n8) return;
    long e = id * 8;
    int n = (int)(e / K);
    int k = (int)(e - (long)n * K);
    float sc = scales[(size_t)n * numGroups + (k >> 7)];   // GROUP_SIZE = 128
    intx4 w0 = *(const intx4*)(Wq + e);
    intx4 w1 = *(const intx4*)(Wq + e + 4);
    bf16x8 o;
#pragma unroll
    for (int q = 0; q < 4; q++) o[q]     = (__bf16)((float)w0[q] * sc);
#pragma unroll
    for (int q = 0; q < 4; q++) o[4 + q] = (__bf16)((float)w1[q] * sc);
    *(bf16x8*)(Wb + e) = o;
}

// ---------------------------------------------------------------------------
// Stage 2: pure bf16 GEMM, C = A * B^T + bias.
//  - 128x128 tile, 4 waves (2x2), each wave 64x64 = 4x4 of 16x16x32 MFMA.
//  - Double-buffered LDS + register prefetch of next K-tile: loads issued
//    BEFORE the MFMA block so HBM/L2 latency hides under compute.
//    One barrier per K-step.
//  - XOR-swizzled LDS: row r (64 B) holds source 16B-slot s at slot
//    s ^ ((r>>1)&3) -> ds_read_b128 fragment reads touch 64 distinct 16B
//    slots per wave (conflict-free); writes stay balanced.
//  - Raster: XCD-bijective swizzle + GROUP_M=8 so concurrent blocks share
//    W panels across XCDs (L3) and A strips within an XCD (L2/L3).
// ---------------------------------------------------------------------------
__global__ __launch_bounds__(256, 4)
void gemm_bb(const __bf16* __restrict__ A, const __bf16* __restrict__ B,
             const float* __restrict__ bias, float* __restrict__ C,
             int M, int N, int K)
{
    __shared__ __bf16 sA[2][BM * BK];   // 8 KB each buffer
    __shared__ __bf16 sB[2][BN * BK];   // total LDS = 32 KB

    const int t    = threadIdx.x;
    const int lane = t & 63;
    const int wave = t >> 6;
    const int wr   = wave >> 1;
    const int wc   = wave & 1;

    // ---- block raster ----
    const int nTn = N / BN;
    const int nTm = M / BM;
    const int nwg = (int)gridDim.x;
    int bid = (int)blockIdx.x;
    int wg  = ((nwg & 7) == 0) ? ((bid & 7) * (nwg >> 3) + (bid >> 3)) : bid;
    const int GM = 8;
    int gsz = GM * nTn;
    int gid = wg / gsz;
    int rem = wg - gid * gsz;
    int gm  = nTm - gid * GM; if (gm > GM) gm = GM;
    int tm  = gid * GM + rem % gm;
    int tn  = rem / gm;
    const int bRow = tm * BM;
    const int bCol = tn * BN;

    // ---- staging: thread owns 16 consecutive source elements (2x16B) ----
    const int srow  = t >> 1;               // tile row 0..127
    const int sslot = (t & 1) << 1;         // source slot 0 or 2
    const int sswz  = (srow >> 1) & 3;
    const int wo0   = srow * BK + (((sslot    ) ^ sswz) << 3);
    const int wo1   = srow * BK + (((sslot + 1) ^ sswz) << 3);
    const __bf16* aSrc = A + (size_t)(bRow + srow) * K + (sslot << 3);
    const __bf16* bSrc = B + (size_t)(bCol + srow) * K + (sslot << 3);

    // ---- fragment-read coords (A/B layout: m = lane&15, k = (lane>>4)*8+j)
    const int lrow  = lane & 15;
    const int fslot = ((lane >> 4) ^ ((lrow >> 1) & 3)) << 3;  // swizzled k-slot
    const int aBase = (wr * 64 + lrow) * BK + fslot;
    const int bBase = (wc * 64 + lrow) * BK + fslot;

    floatx4 acc[4][4];
#pragma unroll
    for (int i = 0; i < 4; i++)
#pragma unroll
        for (int j = 0; j < 4; j++) acc[i][j] = (floatx4)0.f;

    uintx4 pa0, pa1, pb0, pb1;

#define PREFETCH(K0) do {                                   \
    const uintx4* ap_ = (const uintx4*)(aSrc + (K0));       \
    const uintx4* bp_ = (const uintx4*)(bSrc + (K0));       \
    pa0 = ap_[0]; pa1 = ap_[1];                             \
    pb0 = bp_[0]; pb1 = bp_[1];                             \
} while (0)

#define STORE_LDS(buf) do {                                 \
    *(uintx4*)(&sA[buf][wo0]) = pa0;                        \
    *(uintx4*)(&sA[buf][wo1]) = pa1;                        \
    *(uintx4*)(&sB[buf][wo0]) = pb0;                        \
    *(uintx4*)(&sB[buf][wo1]) = pb1;                        \
} while (0)

#define MFMA_STEP(buf) do {                                                    \
    bf16x8 af_[4], bf_[4];                                                     \
    _Pragma("unroll")                                                          \
    for (int i_ = 0; i_ < 4; i_++)                                             \
        af_[i_] = *(const bf16x8*)(&sA[buf][aBase + i_ * 16 * BK]);            \
    _Pragma("unroll")                                                          \
    for (int j_ = 0; j_ < 4; j_++)                                             \
        bf_[j_] = *(const bf16x8*)(&sB[buf][bBase + j_ * 16 * BK]);            \
    _Pragma("unroll")                                                          \
    for (int i_ = 0; i_ < 4; i_++)                                             \
    _Pragma("unroll")                                                          \
    for (int j_ = 0; j_ < 4; j_++)                                             \
        acc[i_][j_] = __builtin_amdgcn_mfma_f32_16x16x32_bf16(                 \
            af_[i_], bf_[j_], acc[i_][j_], 0, 0, 0);                           \
} while (0)

    PREFETCH(0);
    STORE_LDS(0);
    __syncthreads();

    int k0 = 0;
    for (; k0 + 2 * BK < K; k0 += 2 * BK) {
        PREFETCH(k0 + BK);        // loads in flight during MFMA below
        MFMA_STEP(0);
        STORE_LDS(1);
        __syncthreads();
        PREFETCH(k0 + 2 * BK);
        MFMA_STEP(1);
        STORE_LDS(0);
        __syncthreads();
    }
    // k0 == K - 2*BK
    PREFETCH(k0 + BK);
    MFMA_STEP(0);
    STORE_LDS(1);
    __syncthreads();
    MFMA_STEP(1);

#undef PREFETCH
#undef STORE_LDS
#undef MFMA_STEP

    // ---- epilogue: C/D layout col = lane&15, row = (lane>>4)*4 + reg ----
    const int lq = lane >> 4;
#pragma unroll
    for (int j = 0; j < 4; j++) {
        int gc = bCol + wc * 64 + j * 16 + lrow;
        float bb = bias[gc];
#pragma unroll
        for (int i = 0; i < 4; i++) {
            int gr0 = bRow + wr * 64 + i * 16 + lq * 4;
#pragma unroll
            for (int r = 0; r < 4; r++)
                C[(size_t)(gr0 + r) * N + gc] = acc[i][j][r] + bb;
        }
    }
}

// ---------------------------------------------------------------------------
// Fallback: previous harness-verified fused kernel (used if ws too small).
// ---------------------------------------------------------------------------
__global__ __launch_bounds__(256)
void gemm_dq(const float* __restrict__ A,
             const int*   __restrict__ Wq,
             const float* __restrict__ scales,
             const float* __restrict__ bias,
             float*       __restrict__ C,
             int M, int N, int K, int numGroups)
{
    __shared__ __bf16 sA[BM * BK];
    __shared__ __bf16 sB[BN * BK];

    const int t    = threadIdx.x;
    const int lane = t & 63;
    const int wave = t >> 6;
    const int wr   = wave >> 1;
    const int wc   = wave & 1;
    const int bRow = blockIdx.y * BM;
    const int bCol = blockIdx.x * BN;

    floatx4 acc[4][4];
#pragma unroll
    for (int i = 0; i < 4; i++)
#pragma unroll
        for (int j = 0; j < 4; j++)
            acc[i][j] = (floatx4)0.f;

    int aRow[2], aKe[2];
#pragma unroll
    for (int s = 0; s < 2; s++) {
        int eo  = (s * 256 + t) * 8;
        aRow[s] = eo >> 5;
        aKe[s]  = eo & 31;
    }

    const int fRow = t >> 1;
    const int fK   = (t & 1) << 4;
    const size_t wBase  = (size_t)(bCol + fRow) * (size_t)K;
    const size_t scBase = (size_t)(bCol + fRow) * (size_t)numGroups;

    const int lrow = lane & 15;
    const int lk   = (lane >> 4) << 3;

    for (int k0 = 0; k0 < K; k0 += BK) {
        bf16x8 av[2];
#pragma unroll
        for (int s = 0; s < 2; s++) {
            const floatx4* ap =
                (const floatx4*)(A + (size_t)(bRow + aRow[s]) * K + k0 + aKe[s]);
            floatx4 f0 = ap[0];
            floatx4 f1 = ap[1];
#pragma unroll
            for (int e = 0; e < 4; e++) av[s][e]     = (__bf16)f0[e];
#pragma unroll
            for (int e = 0; e < 4; e++) av[s][4 + e] = (__bf16)f1[e];
        }

        float sc = scales[scBase + (k0 >> 7)];
        intx4 w[4];
#pragma unroll
        for (int q = 0; q < 4; q++)
            w[q] = *(const intx4*)(Wq + wBase + (size_t)(k0 + fK + 4 * q));

        bf16x8 b0, b1;
#pragma unroll
        for (int e = 0; e < 8; e++)
            b0[e] = (__bf16)((float)w[e >> 2][e & 3] * sc);
#pragma unroll
        for (int e = 0; e < 8; e++)
            b1[e] = (__bf16)((float)w[2 + (e >> 2)][e & 3] * sc);

        __syncthreads();
        *(bf16x8*)(sA + aRow[0] * BK + aKe[0]) = av[0];
        *(bf16x8*)(sA + aRow[1] * BK + aKe[1]) = av[1];
        *(bf16x8*)(sB + fRow * BK + fK)        = b0;
        *(bf16x8*)(sB + fRow * BK + fK + 8)    = b1;
        __syncthreads();

        bf16x8 af[4], bfr[4];
#pragma unroll
        for (int i = 0; i < 4; i++)
            af[i] = *(const bf16x8*)(sA + (wr * 64 + i * 16 + lrow) * BK + lk);
#pragma unroll
        for (int j = 0; j < 4; j++)
            bfr[j] = *(const bf16x8*)(sB + (wc * 64 + j * 16 + lrow) * BK + lk);

#pragma unroll
        for (int i = 0; i < 4; i++)
#pragma unroll
            for (int j = 0; j < 4; j++)
                acc[i][j] = __builtin_amdgcn_mfma_f32_16x16x32_bf16(
                    af[i], bfr[j], acc[i][j], 0, 0, 0);
    }

    const int lq = lane >> 4;
#pragma unroll
    for (int j = 0; j < 4; j++) {
        int gc = bCol + wc * 64 + j * 16 + lrow;
        float bb = bias[gc];
#pragma unroll
        for (int i = 0; i < 4; i++) {
            int gr0 = bRow + wr * 64 + i * 16 + lq * 4;
#pragma unroll
            for (int r = 0; r < 4; r++)
                C[(size_t)(gr0 + r) * N + gc] = acc[i][j][r] + bb;
        }
    }
}

// ---------------------------------------------------------------------------
extern "C" void kernel_launch(void* const* d_in, const int* in_sizes, int n_in,
                              void* d_out, int out_size, void* d_ws, size_t ws_size,
                              hipStream_t stream)
{
    const float* x      = (const float*)d_in[0];
    const int*   wq     = (const int*)d_in[1];
    const float* scales = (const float*)d_in[2];
    const float* bias   = (const float*)d_in[3];
    float* out          = (float*)d_out;

    const int  OUT_F  = in_sizes[3];             // 11008
    const long wtotal = (long)in_sizes[1];       // OUT_F * K
    const int  K      = (int)(wtotal / OUT_F);   // 4096
    const int  M      = in_sizes[0] / K;         // 8192 (= B*S)
    const int  N      = OUT_F;
    const int  numGroups = in_sizes[2] / OUT_F;  // 32

    const size_t bytesA = (size_t)M * K * sizeof(__bf16);   // 67 MB
    const size_t bytesW = (size_t)N * K * sizeof(__bf16);   // 90 MB

    const bool fast = (ws_size >= bytesA + bytesW) &&
                      (M % BM) == 0 && (N % BN) == 0 &&
                      (K % (2 * BK)) == 0 && (K == numGroups * 128);

    if (fast) {
        __bf16* Ab = (__bf16*)d_ws;
        __bf16* Wb = (__bf16*)((char*)d_ws + bytesA);
        long a8 = (long)M * K / 8;
        long w8 = (long)N * K / 8;
        conv_a<<<dim3((unsigned)((a8 + 255) / 256)), dim3(256), 0, stream>>>(x, Ab, a8);
        conv_w<<<dim3((unsigned)((w8 + 255) / 256)), dim3(256), 0, stream>>>(
            wq, scales, Wb, K, numGroups, w8);
        gemm_bb<<<dim3((unsigned)((M / BM) * (N / BN))), dim3(256), 0, stream>>>(
            Ab, Wb, bias, out, M, N, K);
    } else {
        dim3 grid(N / BN, M / BM);
        gemm_dq<<<grid, dim3(256), 0, stream>>>(x, wq, scales, bias, out,
                                                M, N, K, numGroups);
    }
}

// Round 2
// 1187.698 us; speedup vs baseline: 2.3421x; 1.2895x over previous
//
#include <hip/hip_runtime.h>
#include <hip/hip_bf16.h>
#include <stdint.h>

typedef __bf16 bf16x8  __attribute__((ext_vector_type(8)));
typedef float  floatx4 __attribute__((ext_vector_type(4)));
typedef int    intx4   __attribute__((ext_vector_type(4)));

// ---------------------------------------------------------------------------
// Stage 1a: A fp32 -> bf16.
// ---------------------------------------------------------------------------
__global__ __launch_bounds__(256)
void conv_a(const float* __restrict__ A, __bf16* __restrict__ Ab, long n8)
{
    long id = (long)blockIdx.x * 256 + threadIdx.x;
    if (id >= n8) return;
    const float* p = A + id * 8;
    floatx4 f0 = *(const floatx4*)p;
    floatx4 f1 = *(const floatx4*)(p + 4);
    bf16x8 o;
#pragma unroll
    for (int e = 0; e < 4; e++) o[e]     = (__bf16)f0[e];
#pragma unroll
    for (int e = 0; e < 4; e++) o[4 + e] = (__bf16)f1[e];
    *(bf16x8*)(Ab + id * 8) = o;
}

// ---------------------------------------------------------------------------
// Stage 1b: W int32 * scale -> bf16 (identical arithmetic to the fused path).
// ---------------------------------------------------------------------------
__global__ __launch_bounds__(256)
void conv_w(const int* __restrict__ Wq, const float* __restrict__ scales,
            __bf16* __restrict__ Wb, int K, int numGroups, long n8)
{
    long id = (long)blockIdx.x * 256 + threadIdx.x;
    if (id >= n8) return;
    long e = id * 8;
    int n = (int)(e / K);
    int k = (int)(e - (long)n * K);
    float sc = scales[(size_t)n * numGroups + (k >> 7)];   // GROUP_SIZE = 128
    intx4 w0 = *(const intx4*)(Wq + e);
    intx4 w1 = *(const intx4*)(Wq + e + 4);
    bf16x8 o;
#pragma unroll
    for (int q = 0; q < 4; q++) o[q]     = (__bf16)((float)w0[q] * sc);
#pragma unroll
    for (int q = 0; q < 4; q++) o[4 + q] = (__bf16)((float)w1[q] * sc);
    *(bf16x8*)(Wb + e) = o;
}

// ---------------------------------------------------------------------------
// global -> LDS direct (width 16). LDS dest is wave-uniform base + lane*16.
// ---------------------------------------------------------------------------
__device__ __forceinline__ void gload_lds16(const __bf16* g, __bf16* l)
{
    auto gp = reinterpret_cast<const __attribute__((address_space(1))) void*>(
        reinterpret_cast<uintptr_t>(g));
    auto lp = reinterpret_cast<__attribute__((address_space(3))) void*>(
        reinterpret_cast<uintptr_t>(l));
    __builtin_amdgcn_global_load_lds(gp, lp, 16, 0, 0);
}

// ---------------------------------------------------------------------------
// Stage 2: 256x256 8-phase bf16 GEMM (T1+T2+T3+T4+T5).
//  - 512 thr / 8 waves (2M x 4N); per-wave 128x64 C = acc[8][4] 16x16 frags.
//  - BK=64; LDS 2 x (A 32KB + B 32KB) = 128 KB, staged by global_load_lds
//    width 16 (linear dest), XOR-swizzle applied on BOTH sides: source col16
//    pre-swizzled (col ^ row&7) and ds_read slot swizzled the same way ->
//    conflict-free ds_read_b128 by construction (rule 21).
//  - 4 phases/K-tile; stage groups ordered by NEXT tile's read-phase need:
//      ph1 stages a1(t+1) [A rows needed at next ph1]
//      ph2 stages b1(t+1) [B rows needed at next ph1]
//      ph3 stages b2(t+1) [B rows needed at next ph2]
//      ph4 stages a3(t+1) [A rows needed at next ph3]
//    Counted vmcnt(4) at ends of ph1/ph2/ph4 retires exactly the group the
//    following phase reads; 2 groups always stay in flight (never drains).
//    Last tile peeled with vmcnt 2/0.
//  - Every read-gating s_barrier is preceded by a memory-clobber s_waitcnt,
//    so ds_reads cannot hoist above the cross-wave landing gate.
// ---------------------------------------------------------------------------
__global__ __launch_bounds__(512, 2)
void gemm8(const __bf16* __restrict__ A, const __bf16* __restrict__ B,
           const float* __restrict__ bias, float* __restrict__ C,
           int M, int N, int K)
{
    __shared__ __bf16 sA[2][16384];   // [buf][256 rows x 64 cols]
    __shared__ __bf16 sB[2][16384];

    const int t    = threadIdx.x;
    const int lane = t & 63;
    const int wave = t >> 6;
    const int wr   = wave >> 2;       // 0..1 -> 128-row strip of C
    const int wc   = wave & 3;        // 0..3 -> 64-col strip of C

    // ---- raster: XCD-bijective swizzle + GROUP_M chunking ----
    const int nTn = N >> 8, nTm = M >> 8;
    const int nwg = nTm * nTn;
    int bid = (int)blockIdx.x;
    int wg  = ((nwg & 7) == 0) ? ((bid & 7) * (nwg >> 3) + (bid >> 3)) : bid;
    const int GM = 8;
    int gsz = GM * nTn;
    int gid = wg / gsz;
    int rem = wg - gid * gsz;
    int gm  = nTm - gid * GM; if (gm > GM) gm = GM;
    const int bRow = (gid * GM + rem % gm) << 8;
    const int bCol = (rem / gm) << 8;

    // ---- fragment read addressing (swizzled k-slot) ----
    const int l15 = lane & 15;
    const int l4  = lane >> 4;
    const int sl0 = l4 ^ (l15 & 7);          // k-step 0 16B-slot
    const int aOff0 = (wr * 128 + l15) * 64 + sl0 * 8;
    const int aOff1 = (wr * 128 + l15) * 64 + (sl0 ^ 4) * 8;
    const int bOff0 = (wc * 64 + l15) * 64 + sl0 * 8;
    const int bOff1 = (wc * 64 + l15) * 64 + (sl0 ^ 4) * 8;

    // ---- stage addressing: chunk = 1024B = 8 rows; lane covers 16B ----
    const int srow = lane >> 3;              // row within chunk (0..7)
    const int scol = (lane & 7) ^ srow;      // pre-swizzled 16B col
    // per-wave chunk bases per group (chunk c = LDS rows 8c..8c+7):
    const int cA1 = (wave < 4) ? 2 * wave : 2 * wave + 8;        // rows 0-63,128-191
    const int cA3 = cA1 + 8;                                     // rows 64-127,192-255
    const int cB1 = (wave >> 1) * 8 + (wave & 1) * 2;            // rows 0-31,64-95,128-159,192-223
    const int cB2 = cB1 + 4;                                     // the other B rows

#define STAGE_A(c, buf, k0) \
    gload_lds16(A + (size_t)(bRow + (c) * 8 + srow) * K + (k0) + scol * 8, \
                &sA[buf][(c) * 512])
#define STAGE_B(c, buf, k0) \
    gload_lds16(B + (size_t)(bCol + (c) * 8 + srow) * K + (k0) + scol * 8, \
                &sB[buf][(c) * 512])

#define VMCNT(n) asm volatile("s_waitcnt vmcnt(" #n ")" ::: "memory")
#define LGKM0()  asm volatile("s_waitcnt lgkmcnt(0)" ::: "memory")
#define BAR()    __builtin_amdgcn_s_barrier()
#define SCHED0() __builtin_amdgcn_sched_barrier(0)
#define PRIO1()  __builtin_amdgcn_s_setprio(1)
#define PRIO0()  __builtin_amdgcn_s_setprio(0)

    floatx4 acc[8][4];
#pragma unroll
    for (int i = 0; i < 8; i++)
#pragma unroll
        for (int j = 0; j < 4; j++) acc[i][j] = (floatx4)0.f;

    bf16x8 aq[4][2];    // current A quadrant [mt][ks]
    bf16x8 b0[2][2];    // B qn0 [nt][ks] (live ph1..ph3)
    bf16x8 b1f[2][2];   // B qn1 [nt][ks] (live ph2..ph4)

#define LDA(QM, BUF) do { _Pragma("unroll")                                    \
    for (int m_ = 0; m_ < 4; m_++) {                                           \
        aq[m_][0] = *(const bf16x8*)(&sA[BUF][aOff0 + ((QM)*4 + m_) * 1024]);  \
        aq[m_][1] = *(const bf16x8*)(&sA[BUF][aOff1 + ((QM)*4 + m_) * 1024]);  \
    } } while (0)
#define LDB(QN, DST, BUF) do { _Pragma("unroll")                               \
    for (int n_ = 0; n_ < 2; n_++) {                                           \
        DST[n_][0] = *(const bf16x8*)(&sB[BUF][bOff0 + ((QN)*2 + n_) * 1024]); \
        DST[n_][1] = *(const bf16x8*)(&sB[BUF][bOff1 + ((QN)*2 + n_) * 1024]); \
    } } while (0)
#define MM(QM, QN, BSRC) do { _Pragma("unroll")                                \
    for (int m_ = 0; m_ < 4; m_++) { _Pragma("unroll")                         \
    for (int n_ = 0; n_ < 2; n_++) { _Pragma("unroll")                         \
    for (int k_ = 0; k_ < 2; k_++)                                             \
        acc[(QM)*4 + m_][(QN)*2 + n_] =                                        \
            __builtin_amdgcn_mfma_f32_16x16x32_bf16(                           \
                aq[m_][k_], BSRC[n_][k_], acc[(QM)*4 + m_][(QN)*2 + n_],       \
                0, 0, 0);                                                      \
    } } } while (0)

#define TILE(BUF, TT, LAST) do {                                               \
    const int k1_ = ((TT) + 1) << 6;                                           \
    /* phase 1: A(qm0) + B(qn0); stage a1(t+1) */                              \
    LDA(0, BUF); LDB(0, b0, BUF);                                              \
    if (!(LAST)) { STAGE_A(cA1, (BUF) ^ 1, k1_); STAGE_A(cA1 + 1, (BUF) ^ 1, k1_); } \
    BAR(); LGKM0(); SCHED0();                                                  \
    PRIO1(); MM(0, 0, b0); PRIO0();                                            \
    if (LAST) { VMCNT(2); } else { VMCNT(4); }                                 \
    BAR();                                                                     \
    /* phase 2: B(qn1); stage b1(t+1) */                                       \
    LDB(1, b1f, BUF);                                                          \
    if (!(LAST)) { STAGE_B(cB1, (BUF) ^ 1, k1_); STAGE_B(cB1 + 1, (BUF) ^ 1, k1_); } \
    BAR(); LGKM0(); SCHED0();                                                  \
    PRIO1(); MM(0, 1, b1f); PRIO0();                                           \
    if (LAST) { VMCNT(0); } else { VMCNT(4); }                                 \
    BAR();                                                                     \
    /* phase 3: A(qm1); stage b2(t+1) */                                       \
    LDA(1, BUF);                                                               \
    if (!(LAST)) { STAGE_B(cB2, (BUF) ^ 1, k1_); STAGE_B(cB2 + 1, (BUF) ^ 1, k1_); } \
    BAR(); LGKM0(); SCHED0();                                                  \
    PRIO1(); MM(1, 0, b0); PRIO0();                                            \
    BAR();                                                                     \
    /* phase 4: stage a3(t+1) */                                               \
    if (!(LAST)) { STAGE_A(cA3, (BUF) ^ 1, k1_); STAGE_A(cA3 + 1, (BUF) ^ 1, k1_); } \
    BAR(); SCHED0();                                                           \
    PRIO1(); MM(1, 1, b1f); PRIO0();                                           \
    if (!(LAST)) { VMCNT(4); }                                                 \
    BAR();                                                                     \
} while (0)

    // ---- prologue: stage tile 0 (order a1,b1,b2,a3), retire a1+b1 ----
    STAGE_A(cA1, 0, 0); STAGE_A(cA1 + 1, 0, 0);
    STAGE_B(cB1, 0, 0); STAGE_B(cB1 + 1, 0, 0);
    STAGE_B(cB2, 0, 0); STAGE_B(cB2 + 1, 0, 0);
    STAGE_A(cA3, 0, 0); STAGE_A(cA3 + 1, 0, 0);
    VMCNT(4);
    BAR();

    const int NT = K >> 6;
    for (int tt = 0; tt + 2 < NT; tt += 2) {
        TILE(0, tt, 0);
        TILE(1, tt + 1, 0);
    }
    TILE(0, NT - 2, 0);
    TILE(1, NT - 1, 1);

#undef TILE
#undef MM
#undef LDB
#undef LDA
#undef STAGE_A
#undef STAGE_B

    // ---- epilogue: C/D layout col = lane&15, row = (lane>>4)*4 + reg ----
#pragma unroll
    for (int nt = 0; nt < 4; nt++) {
        const int gc = bCol + wc * 64 + nt * 16 + l15;
        const float bb = bias[gc];
#pragma unroll
        for (int mt = 0; mt < 8; mt++) {
            const int gr0 = bRow + wr * 128 + mt * 16 + l4 * 4;
#pragma unroll
            for (int r = 0; r < 4; r++)
                C[(size_t)(gr0 + r) * N + gc] = acc[mt][nt][r] + bb;
        }
    }
}

// ---------------------------------------------------------------------------
// Fallback: original harness-verified fused kernel (any-shape safety net).
// ---------------------------------------------------------------------------
constexpr int FBM = 128;
constexpr int FBN = 128;
constexpr int FBK = 32;

__global__ __launch_bounds__(256)
void gemm_dq(const float* __restrict__ A,
             const int*   __restrict__ Wq,
             const float* __restrict__ scales,
             const float* __restrict__ bias,
             float*       __restrict__ C,
             int M, int N, int K, int numGroups)
{
    __shared__ __bf16 sA[FBM * FBK];
    __shared__ __bf16 sB[FBN * FBK];

    const int t    = threadIdx.x;
    const int lane = t & 63;
    const int wave = t >> 6;
    const int wr   = wave >> 1;
    const int wc   = wave & 1;
    const int bRow = blockIdx.y * FBM;
    const int bCol = blockIdx.x * FBN;

    floatx4 acc[4][4];
#pragma unroll
    for (int i = 0; i < 4; i++)
#pragma unroll
        for (int j = 0; j < 4; j++)
            acc[i][j] = (floatx4)0.f;

    int aRow[2], aKe[2];
#pragma unroll
    for (int s = 0; s < 2; s++) {
        int eo  = (s * 256 + t) * 8;
        aRow[s] = eo >> 5;
        aKe[s]  = eo & 31;
    }

    const int fRow = t >> 1;
    const int fK   = (t & 1) << 4;
    const size_t wBase  = (size_t)(bCol + fRow) * (size_t)K;
    const size_t scBase = (size_t)(bCol + fRow) * (size_t)numGroups;

    const int lrow = lane & 15;
    const int lk   = (lane >> 4) << 3;

    for (int k0 = 0; k0 < K; k0 += FBK) {
        bf16x8 av[2];
#pragma unroll
        for (int s = 0; s < 2; s++) {
            const floatx4* ap =
                (const floatx4*)(A + (size_t)(bRow + aRow[s]) * K + k0 + aKe[s]);
            floatx4 f0 = ap[0];
            floatx4 f1 = ap[1];
#pragma unroll
            for (int e = 0; e < 4; e++) av[s][e]     = (__bf16)f0[e];
#pragma unroll
            for (int e = 0; e < 4; e++) av[s][4 + e] = (__bf16)f1[e];
        }

        float sc = scales[scBase + (k0 >> 7)];
        intx4 w[4];
#pragma unroll
        for (int q = 0; q < 4; q++)
            w[q] = *(const intx4*)(Wq + wBase + (size_t)(k0 + fK + 4 * q));

        bf16x8 b0, b1;
#pragma unroll
        for (int e = 0; e < 8; e++)
            b0[e] = (__bf16)((float)w[e >> 2][e & 3] * sc);
#pragma unroll
        for (int e = 0; e < 8; e++)
            b1[e] = (__bf16)((float)w[2 + (e >> 2)][e & 3] * sc);

        __syncthreads();
        *(bf16x8*)(sA + aRow[0] * FBK + aKe[0]) = av[0];
        *(bf16x8*)(sA + aRow[1] * FBK + aKe[1]) = av[1];
        *(bf16x8*)(sB + fRow * FBK + fK)        = b0;
        *(bf16x8*)(sB + fRow * FBK + fK + 8)    = b1;
        __syncthreads();

        bf16x8 af[4], bfr[4];
#pragma unroll
        for (int i = 0; i < 4; i++)
            af[i] = *(const bf16x8*)(sA + (wr * 64 + i * 16 + lrow) * FBK + lk);
#pragma unroll
        for (int j = 0; j < 4; j++)
            bfr[j] = *(const bf16x8*)(sB + (wc * 64 + j * 16 + lrow) * FBK + lk);

#pragma unroll
        for (int i = 0; i < 4; i++)
#pragma unroll
            for (int j = 0; j < 4; j++)
                acc[i][j] = __builtin_amdgcn_mfma_f32_16x16x32_bf16(
                    af[i], bfr[j], acc[i][j], 0, 0, 0);
    }

    const int lq = lane >> 4;
#pragma unroll
    for (int j = 0; j < 4; j++) {
        int gc = bCol + wc * 64 + j * 16 + lrow;
        float bb = bias[gc];
#pragma unroll
        for (int i = 0; i < 4; i++) {
            int gr0 = bRow + wr * 64 + i * 16 + lq * 4;
#pragma unroll
            for (int r = 0; r < 4; r++)
                C[(size_t)(gr0 + r) * N + gc] = acc[i][j][r] + bb;
        }
    }
}

// ---------------------------------------------------------------------------
extern "C" void kernel_launch(void* const* d_in, const int* in_sizes, int n_in,
                              void* d_out, int out_size, void* d_ws, size_t ws_size,
                              hipStream_t stream)
{
    const float* x      = (const float*)d_in[0];
    const int*   wq     = (const int*)d_in[1];
    const float* scales = (const float*)d_in[2];
    const float* bias   = (const float*)d_in[3];
    float* out          = (float*)d_out;

    const int  OUT_F  = in_sizes[3];             // 11008
    const long wtotal = (long)in_sizes[1];       // OUT_F * K
    const int  K      = (int)(wtotal / OUT_F);   // 4096
    const int  M      = in_sizes[0] / K;         // 8192 (= B*S)
    const int  N      = OUT_F;
    const int  numGroups = in_sizes[2] / OUT_F;  // 32

    const size_t bytesA = (size_t)M * K * sizeof(__bf16);   // 67 MB
    const size_t bytesW = (size_t)N * K * sizeof(__bf16);   // 90 MB

    const bool fast256 = (ws_size >= bytesA + bytesW) &&
                         (M % 256) == 0 && (N % 256) == 0 &&
                         (K % 128) == 0 && K >= 128 &&
                         (K == numGroups * 128);

    if (fast256) {
        __bf16* Ab = (__bf16*)d_ws;
        __bf16* Wb = (__bf16*)((char*)d_ws + bytesA);
        long a8 = (long)M * K / 8;
        long w8 = (long)N * K / 8;
        conv_a<<<dim3((unsigned)((a8 + 255) / 256)), dim3(256), 0, stream>>>(x, Ab, a8);
        conv_w<<<dim3((unsigned)((w8 + 255) / 256)), dim3(256), 0, stream>>>(
            wq, scales, Wb, K, numGroups, w8);
        gemm8<<<dim3((unsigned)((M >> 8) * (N >> 8))), dim3(512), 0, stream>>>(
            Ab, Wb, bias, out, M, N, K);
    } else {
        dim3 grid(N / FBN, M / FBM);
        gemm_dq<<<grid, dim3(256), 0, stream>>>(x, wq, scales, bias, out,
                                                M, N, K, numGroups);
    }
}

// Round 3
// 1175.795 us; speedup vs baseline: 2.3658x; 1.0101x over previous
//
#include <hip/hip_runtime.h>
#include <hip/hip_bf16.h>
#include <stdint.h>

typedef __bf16 bf16x8  __attribute__((ext_vector_type(8)));
typedef float  floatx4 __attribute__((ext_vector_type(4)));
typedef int    intx4   __attribute__((ext_vector_type(4)));

// ---------------------------------------------------------------------------
// Stage 1a: A fp32 -> bf16.
// ---------------------------------------------------------------------------
__global__ __launch_bounds__(256)
void conv_a(const float* __restrict__ A, __bf16* __restrict__ Ab, long n8)
{
    long id = (long)blockIdx.x * 256 + threadIdx.x;
    if (id >= n8) return;
    const float* p = A + id * 8;
    floatx4 f0 = *(const floatx4*)p;
    floatx4 f1 = *(const floatx4*)(p + 4);
    bf16x8 o;
#pragma unroll
    for (int e = 0; e < 4; e++) o[e]     = (__bf16)f0[e];
#pragma unroll
    for (int e = 0; e < 4; e++) o[4 + e] = (__bf16)f1[e];
    *(bf16x8*)(Ab + id * 8) = o;
}

// ---------------------------------------------------------------------------
// Stage 1b: W int32 * scale -> bf16 (identical arithmetic to the fused path).
// ---------------------------------------------------------------------------
__global__ __launch_bounds__(256)
void conv_w(const int* __restrict__ Wq, const float* __restrict__ scales,
            __bf16* __restrict__ Wb, int K, int numGroups, long n8)
{
    long id = (long)blockIdx.x * 256 + threadIdx.x;
    if (id >= n8) return;
    long e = id * 8;
    int n = (int)(e / K);
    int k = (int)(e - (long)n * K);
    float sc = scales[(size_t)n * numGroups + (k >> 7)];   // GROUP_SIZE = 128
    intx4 w0 = *(const intx4*)(Wq + e);
    intx4 w1 = *(const intx4*)(Wq + e + 4);
    bf16x8 o;
#pragma unroll
    for (int q = 0; q < 4; q++) o[q]     = (__bf16)((float)w0[q] * sc);
#pragma unroll
    for (int q = 0; q < 4; q++) o[4 + q] = (__bf16)((float)w1[q] * sc);
    *(bf16x8*)(Wb + e) = o;
}

// ---------------------------------------------------------------------------
// global -> LDS direct (width 16). LDS dest is wave-uniform base + lane*16.
// ---------------------------------------------------------------------------
__device__ __forceinline__ void gload_lds16(const __bf16* g, __bf16* l)
{
    auto gp = reinterpret_cast<const __attribute__((address_space(1))) void*>(
        reinterpret_cast<uintptr_t>(g));
    auto lp = reinterpret_cast<__attribute__((address_space(3))) void*>(
        reinterpret_cast<uintptr_t>(l));
    __builtin_amdgcn_global_load_lds(gp, lp, 16, 0, 0);
}

// ---------------------------------------------------------------------------
// Stage 2: 256x256 8-phase bf16 GEMM, deepened pipeline (distance-5 staging).
//
// Read schedule per tile t (buffer b = t&1):
//   ph1 reads A-half0 (cA1 chunks) + B-half0 (cB1); ph2 reads B-half1 (cB2);
//   ph3 reads A-half1 (cA3); ph4 reads nothing.
// Stage schedule (uniform 5-phase issue->read distance):
//   ph1 stages B-half1(t+1) -> b^1     (read at t+1 ph2)
//   ph2 stages A-half1(t+1) -> b^1     (read at t+1 ph3)
//   ph4 stages A-half0+B-half0(t+2) -> b  (read at t+2 ph1; chunks of b are
//        dead after t's ph1 lgkmcnt(0), which precedes ph3's closing barrier,
//        so the overwrite is race-free)
// Wait ledger (per-wave issues ph1:2 ph2:2 ph3:0 ph4:4, steady outstanding
// 8..12): vmcnt(8) at ends of ph1/ph2/ph4 retires exactly the 4-phase-old
// group the next phase reads; ph3 has NO vmcnt. Peel: tile NT-2 (8,8,4),
// tile NT-1 (2,0,-). Every read-gating barrier is preceded by the
// memory-clobber s_waitcnt so reads cannot hoist above the landing gate.
// ---------------------------------------------------------------------------
__global__ __launch_bounds__(512, 2)
void gemm8(const __bf16* __restrict__ A, const __bf16* __restrict__ B,
           const float* __restrict__ bias, float* __restrict__ C,
           int M, int N, int K)
{
    __shared__ __bf16 sA[2][16384];   // [buf][256 rows x 64 cols]
    __shared__ __bf16 sB[2][16384];

    const int t    = threadIdx.x;
    const int lane = t & 63;
    const int wave = t >> 6;
    const int wr   = wave >> 2;       // 0..1 -> 128-row strip of C
    const int wc   = wave & 3;        // 0..3 -> 64-col strip of C

    // ---- raster: XCD-bijective swizzle + GROUP_M chunking ----
    const int nTn = N >> 8, nTm = M >> 8;
    const int nwg = nTm * nTn;
    int bid = (int)blockIdx.x;
    int wg  = ((nwg & 7) == 0) ? ((bid & 7) * (nwg >> 3) + (bid >> 3)) : bid;
    const int GM = 8;
    int gsz = GM * nTn;
    int gid = wg / gsz;
    int rem = wg - gid * gsz;
    int gm  = nTm - gid * GM; if (gm > GM) gm = GM;
    const int bRow = (gid * GM + rem % gm) << 8;
    const int bCol = (rem / gm) << 8;

    // ---- fragment read addressing (swizzled k-slot) ----
    const int l15 = lane & 15;
    const int l4  = lane >> 4;
    const int sl0 = l4 ^ (l15 & 7);          // k-step 0 16B-slot
    const int aOff0 = (wr * 128 + l15) * 64 + sl0 * 8;
    const int aOff1 = (wr * 128 + l15) * 64 + (sl0 ^ 4) * 8;
    const int bOff0 = (wc * 64 + l15) * 64 + sl0 * 8;
    const int bOff1 = (wc * 64 + l15) * 64 + (sl0 ^ 4) * 8;

    // ---- stage addressing: chunk = 1024B = 8 rows; lane covers 16B ----
    const int srow = lane >> 3;              // row within chunk (0..7)
    const int scol = (lane & 7) ^ srow;      // pre-swizzled 16B col
    // per-wave chunk bases per group (chunk c = LDS rows 8c..8c+7):
    const int cA1 = (wave < 4) ? 2 * wave : 2 * wave + 8;   // A rows 0-63,128-191
    const int cA3 = cA1 + 8;                                // A rows 64-127,192-255
    const int cB1 = (wave >> 1) * 8 + (wave & 1) * 2;       // B rows 0-31,64-95,...
    const int cB2 = cB1 + 4;                                // the other B rows

#define STAGE_A(c, buf, k0) \
    gload_lds16(A + (size_t)(bRow + (c) * 8 + srow) * K + (k0) + scol * 8, \
                &sA[buf][(c) * 512])
#define STAGE_B(c, buf, k0) \
    gload_lds16(B + (size_t)(bCol + (c) * 8 + srow) * K + (k0) + scol * 8, \
                &sB[buf][(c) * 512])

#define VMCNT(n) asm volatile("s_waitcnt vmcnt(" #n ")" ::: "memory")
#define LGKM0()  asm volatile("s_waitcnt lgkmcnt(0)" ::: "memory")
#define BAR()    __builtin_amdgcn_s_barrier()
#define SCHED0() __builtin_amdgcn_sched_barrier(0)
#define PRIO1()  __builtin_amdgcn_s_setprio(1)
#define PRIO0()  __builtin_amdgcn_s_setprio(0)

    floatx4 acc[8][4];
#pragma unroll
    for (int i = 0; i < 8; i++)
#pragma unroll
        for (int j = 0; j < 4; j++) acc[i][j] = (floatx4)0.f;

    bf16x8 aq[4][2];    // current A quadrant [mt][ks]
    bf16x8 b0[2][2];    // B half0 [nt][ks] (live ph1..ph3)
    bf16x8 b1f[2][2];   // B half1 [nt][ks] (live ph2..ph4)

#define LDA(QM, BUF) do { _Pragma("unroll")                                    \
    for (int m_ = 0; m_ < 4; m_++) {                                           \
        aq[m_][0] = *(const bf16x8*)(&sA[BUF][aOff0 + ((QM)*4 + m_) * 1024]);  \
        aq[m_][1] = *(const bf16x8*)(&sA[BUF][aOff1 + ((QM)*4 + m_) * 1024]);  \
    } } while (0)
#define LDB(QN, DST, BUF) do { _Pragma("unroll")                               \
    for (int n_ = 0; n_ < 2; n_++) {                                           \
        DST[n_][0] = *(const bf16x8*)(&sB[BUF][bOff0 + ((QN)*2 + n_) * 1024]); \
        DST[n_][1] = *(const bf16x8*)(&sB[BUF][bOff1 + ((QN)*2 + n_) * 1024]); \
    } } while (0)
#define MM(QM, QN, BSRC) do { _Pragma("unroll")                                \
    for (int m_ = 0; m_ < 4; m_++) { _Pragma("unroll")                         \
    for (int n_ = 0; n_ < 2; n_++) { _Pragma("unroll")                         \
    for (int k_ = 0; k_ < 2; k_++)                                             \
        acc[(QM)*4 + m_][(QN)*2 + n_] =                                        \
            __builtin_amdgcn_mfma_f32_16x16x32_bf16(                           \
                aq[m_][k_], BSRC[n_][k_], acc[(QM)*4 + m_][(QN)*2 + n_],       \
                0, 0, 0);                                                      \
    } } } while (0)

// MODE: 0 = steady, 1 = second-to-last tile, 2 = last tile
#define TILE(BUF, TT, MODE) do {                                               \
    /* ---- phase 1: read A-half0 + B-half0; stage B-half1(t+1) ---- */        \
    LDA(0, BUF); LDB(0, b0, BUF);                                              \
    if ((MODE) != 2) {                                                         \
        const int kn_ = ((TT) + 1) << 6;                                       \
        STAGE_B(cB2, (BUF) ^ 1, kn_); STAGE_B(cB2 + 1, (BUF) ^ 1, kn_);        \
    }                                                                          \
    BAR(); LGKM0(); SCHED0();                                                  \
    PRIO1(); MM(0, 0, b0); PRIO0();                                            \
    if ((MODE) == 2) { VMCNT(2); } else { VMCNT(8); }                          \
    BAR();                                                                     \
    /* ---- phase 2: read B-half1; stage A-half1(t+1) ---- */                  \
    LDB(1, b1f, BUF);                                                          \
    if ((MODE) != 2) {                                                         \
        const int kn_ = ((TT) + 1) << 6;                                       \
        STAGE_A(cA3, (BUF) ^ 1, kn_); STAGE_A(cA3 + 1, (BUF) ^ 1, kn_);        \
    }                                                                          \
    BAR(); LGKM0(); SCHED0();                                                  \
    PRIO1(); MM(0, 1, b1f); PRIO0();                                           \
    if ((MODE) == 2) { VMCNT(0); } else { VMCNT(8); }                          \
    BAR();                                                                     \
    /* ---- phase 3: read A-half1; pure compute, no wait ---- */               \
    LDA(1, BUF);                                                               \
    BAR(); LGKM0(); SCHED0();                                                  \
    PRIO1(); MM(1, 0, b0); PRIO0();                                            \
    BAR();                                                                     \
    /* ---- phase 4: stage A-half0+B-half0(t+2) into CURRENT buf ---- */       \
    if ((MODE) == 0) {                                                         \
        const int kf_ = ((TT) + 2) << 6;                                       \
        STAGE_A(cA1, BUF, kf_); STAGE_A(cA1 + 1, BUF, kf_);                    \
        STAGE_B(cB1, BUF, kf_); STAGE_B(cB1 + 1, BUF, kf_);                    \
    }                                                                          \
    BAR(); SCHED0();                                                           \
    PRIO1(); MM(1, 1, b1f); PRIO0();                                           \
    if ((MODE) == 0) { VMCNT(8); }                                             \
    else if ((MODE) == 1) { VMCNT(4); }                                        \
    BAR();                                                                     \
} while (0)

    // ---- prologue: t0's full buffer + t1's A-half0/B-half0 ----
    STAGE_A(cA1, 0, 0); STAGE_A(cA1 + 1, 0, 0);
    STAGE_B(cB1, 0, 0); STAGE_B(cB1 + 1, 0, 0);
    STAGE_B(cB2, 0, 0); STAGE_B(cB2 + 1, 0, 0);
    STAGE_A(cA3, 0, 0); STAGE_A(cA3 + 1, 0, 0);
    STAGE_A(cA1, 1, 64); STAGE_A(cA1 + 1, 1, 64);
    STAGE_B(cB1, 1, 64); STAGE_B(cB1 + 1, 1, 64);
    VMCNT(8);            // retire t0's A-half0 + B-half0
    BAR();

    const int NT = K >> 6;
    for (int tt = 0; tt + 2 < NT; tt += 2) {
        TILE(0, tt, 0);
        TILE(1, tt + 1, 0);
    }
    TILE(0, NT - 2, 1);
    TILE(1, NT - 1, 2);

#undef TILE
#undef MM
#undef LDB
#undef LDA
#undef STAGE_A
#undef STAGE_B

    // ---- epilogue: C/D layout col = lane&15, row = (lane>>4)*4 + reg ----
    // nontemporal stores: avoid L2 write-allocate fetch of C (was ~360 MB of
    // extra FETCH_SIZE) and keep A/B panels resident.
#pragma unroll
    for (int nt = 0; nt < 4; nt++) {
        const int gc = bCol + wc * 64 + nt * 16 + l15;
        const float bb = bias[gc];
#pragma unroll
        for (int mt = 0; mt < 8; mt++) {
            const int gr0 = bRow + wr * 128 + mt * 16 + l4 * 4;
#pragma unroll
            for (int r = 0; r < 4; r++)
                __builtin_nontemporal_store(acc[mt][nt][r] + bb,
                                            &C[(size_t)(gr0 + r) * N + gc]);
        }
    }
}

// ---------------------------------------------------------------------------
// Fallback: original harness-verified fused kernel (any-shape safety net).
// ---------------------------------------------------------------------------
constexpr int FBM = 128;
constexpr int FBN = 128;
constexpr int FBK = 32;

__global__ __launch_bounds__(256)
void gemm_dq(const float* __restrict__ A,
             const int*   __restrict__ Wq,
             const float* __restrict__ scales,
             const float* __restrict__ bias,
             float*       __restrict__ C,
             int M, int N, int K, int numGroups)
{
    __shared__ __bf16 sA[FBM * FBK];
    __shared__ __bf16 sB[FBN * FBK];

    const int t    = threadIdx.x;
    const int lane = t & 63;
    const int wave = t >> 6;
    const int wr   = wave >> 1;
    const int wc   = wave & 1;
    const int bRow = blockIdx.y * FBM;
    const int bCol = blockIdx.x * FBN;

    floatx4 acc[4][4];
#pragma unroll
    for (int i = 0; i < 4; i++)
#pragma unroll
        for (int j = 0; j < 4; j++)
            acc[i][j] = (floatx4)0.f;

    int aRow[2], aKe[2];
#pragma unroll
    for (int s = 0; s < 2; s++) {
        int eo  = (s * 256 + t) * 8;
        aRow[s] = eo >> 5;
        aKe[s]  = eo & 31;
    }

    const int fRow = t >> 1;
    const int fK   = (t & 1) << 4;
    const size_t wBase  = (size_t)(bCol + fRow) * (size_t)K;
    const size_t scBase = (size_t)(bCol + fRow) * (size_t)numGroups;

    const int lrow = lane & 15;
    const int lk   = (lane >> 4) << 3;

    for (int k0 = 0; k0 < K; k0 += FBK) {
        bf16x8 av[2];
#pragma unroll
        for (int s = 0; s < 2; s++) {
            const floatx4* ap =
                (const floatx4*)(A + (size_t)(bRow + aRow[s]) * K + k0 + aKe[s]);
            floatx4 f0 = ap[0];
            floatx4 f1 = ap[1];
#pragma unroll
            for (int e = 0; e < 4; e++) av[s][e]     = (__bf16)f0[e];
#pragma unroll
            for (int e = 0; e < 4; e++) av[s][4 + e] = (__bf16)f1[e];
        }

        float sc = scales[scBase + (k0 >> 7)];
        intx4 w[4];
#pragma unroll
        for (int q = 0; q < 4; q++)
            w[q] = *(const intx4*)(Wq + wBase + (size_t)(k0 + fK + 4 * q));

        bf16x8 b0, b1;
#pragma unroll
        for (int e = 0; e < 8; e++)
            b0[e] = (__bf16)((float)w[e >> 2][e & 3] * sc);
#pragma unroll
        for (int e = 0; e < 8; e++)
            b1[e] = (__bf16)((float)w[2 + (e >> 2)][e & 3] * sc);

        __syncthreads();
        *(bf16x8*)(sA + aRow[0] * FBK + aKe[0]) = av[0];
        *(bf16x8*)(sA + aRow[1] * FBK + aKe[1]) = av[1];
        *(bf16x8*)(sB + fRow * FBK + fK)        = b0;
        *(bf16x8*)(sB + fRow * FBK + fK + 8)    = b1;
        __syncthreads();

        bf16x8 af[4], bfr[4];
#pragma unroll
        for (int i = 0; i < 4; i++)
            af[i] = *(const bf16x8*)(sA + (wr * 64 + i * 16 + lrow) * FBK + lk);
#pragma unroll
        for (int j = 0; j < 4; j++)
            bfr[j] = *(const bf16x8*)(sB + (wc * 64 + j * 16 + lrow) * FBK + lk);

#pragma unroll
        for (int i = 0; i < 4; i++)
#pragma unroll
            for (int j = 0; j < 4; j++)
                acc[i][j] = __builtin_amdgcn_mfma_f32_16x16x32_bf16(
                    af[i], bfr[j], acc[i][j], 0, 0, 0);
    }

    const int lq = lane >> 4;
#pragma unroll
    for (int j = 0; j < 4; j++) {
        int gc = bCol + wc * 64 + j * 16 + lrow;
        float bb = bias[gc];
#pragma unroll
        for (int i = 0; i < 4; i++) {
            int gr0 = bRow + wr * 64 + i * 16 + lq * 4;
#pragma unroll
            for (int r = 0; r < 4; r++)
                C[(size_t)(gr0 + r) * N + gc] = acc[i][j][r] + bb;
        }
    }
}

// ---------------------------------------------------------------------------
extern "C" void kernel_launch(void* const* d_in, const int* in_sizes, int n_in,
                              void* d_out, int out_size, void* d_ws, size_t ws_size,
                              hipStream_t stream)
{
    const float* x      = (const float*)d_in[0];
    const int*   wq     = (const int*)d_in[1];
    const float* scales = (const float*)d_in[2];
    const float* bias   = (const float*)d_in[3];
    float* out          = (float*)d_out;

    const int  OUT_F  = in_sizes[3];             // 11008
    const long wtotal = (long)in_sizes[1];       // OUT_F * K
    const int  K      = (int)(wtotal / OUT_F);   // 4096
    const int  M      = in_sizes[0] / K;         // 8192 (= B*S)
    const int  N      = OUT_F;
    const int  numGroups = in_sizes[2] / OUT_F;  // 32

    const size_t bytesA = (size_t)M * K * sizeof(__bf16);   // 67 MB
    const size_t bytesW = (size_t)N * K * sizeof(__bf16);   // 90 MB

    const bool fast256 = (ws_size >= bytesA + bytesW) &&
                         (M % 256) == 0 && (N % 256) == 0 &&
                         (K % 128) == 0 && K >= 128 &&
                         (K == numGroups * 128);

    if (fast256) {
        __bf16* Ab = (__bf16*)d_ws;
        __bf16* Wb = (__bf16*)((char*)d_ws + bytesA);
        long a8 = (long)M * K / 8;
        long w8 = (long)N * K / 8;
        conv_a<<<dim3((unsigned)((a8 + 255) / 256)), dim3(256), 0, stream>>>(x, Ab, a8);
        conv_w<<<dim3((unsigned)((w8 + 255) / 256)), dim3(256), 0, stream>>>(
            wq, scales, Wb, K, numGroups, w8);
        gemm8<<<dim3((unsigned)((M >> 8) * (N >> 8))), dim3(512), 0, stream>>>(
            Ab, Wb, bias, out, M, N, K);
    } else {
        dim3 grid(N / FBN, M / FBM);
        gemm_dq<<<grid, dim3(256), 0, stream>>>(x, wq, scales, bias, out,
                                                M, N, K, numGroups);
    }
}